// Round 5
// baseline (135.713 us; speedup 1.0000x reference)
//
#include <hip/hip_runtime.h>
#include <stdint.h>

#define BB      32
#define NN      2000
#define TOPK_   110
#define NBIN    2048
#define CHUNKS  8        // blocks per batch
#define ROWS    256      // diag rows per block

// Phase-multiplexed LDS: diag phase (48 KB) then selection phase (56 KB),
// separated by __syncthreads in the one block that runs both.
union SMem {
    struct {                                  // phase A: diag
        float4 Ps[2048];                      // (p.x,p.y,p.z,b_m)  32 KB
        float  partial[16][256];              //                    16 KB
    } a;
    struct {                                  // phase B: selection
        unsigned long long keys[2048];        // 16 KB
        unsigned long long cand[2048];        // 16 KB
        unsigned int       hist[NBIN];        //  8 KB
        unsigned int       sA[NBIN];          //  8 KB
        unsigned int       sB[NBIN];          //  8 KB
    } b;
};

// ---------------------------------------------------------------------------
// Fused kernel. grid 256 = 32 batches x 8 chunks, block 1024 (16 waves).
//
// Phase A (all blocks): diag[b,row] = softmax(QK^T/sqrt5)[row,row] via the
// bilinear collapse  exponent(n,m) = g_n . p_m + b_m  (row-constant terms
// cancel in the softmax ratio).  Each lane carries 4 rows; wave w covers
// m-chunk [w*125,(w+1)*125) with broadcast LDS reads.
//
// Arrival: threadfence + per-batch atomic counter; the 8th block of a batch
// acquires and runs Phase B (group argmax -> centroid -> distance top-110
// via histogram-select + rank-by-counting) for that batch.
// ---------------------------------------------------------------------------
__global__ __launch_bounds__(1024) void k_fused(
    const float* __restrict__ in_mat,                       // [B,N,3]
    const float* __restrict__ Wi, const float* __restrict__ bi,
    const float* __restrict__ Wq, const float* __restrict__ bq,
    const float* __restrict__ Wk, const float* __restrict__ bk,
    float* __restrict__ diag,                               // [B,N] in d_ws
    unsigned int* __restrict__ counters,                    // [B]   in d_ws
    float* __restrict__ out)                                // [B,110,3]
{
    __shared__ SMem  sm;
    __shared__ float wv[16];
    __shared__ int   wi_[16];
    __shared__ float centroid[3];
    __shared__ int   thrBin, cnt, isLast;

    const int bid   = blockIdx.x;
    const int b     = bid >> 3;
    const int chunk = bid & (CHUNKS - 1);
    const int t     = threadIdx.x;
    const float* inb = in_mat + (size_t)b * NN * 3;

    // ===================== Phase A: diag =====================
    // fold weights: G' = pf*(WiWq)(WiWk)^T (3x3), v' = pf*cq(WiWk)^T (3)
    const float pf = 0.44721359549995793f * 1.4426950408889634f; // 1/sqrt5*log2e
    float Mq[15], Mk[15], cq[5];
#pragma unroll
    for (int d = 0; d < 5; ++d) {
        float s = bq[d];
#pragma unroll
        for (int k = 0; k < 5; ++k) s += bi[k] * Wq[k * 5 + d];
        cq[d] = s;
    }
#pragma unroll
    for (int i = 0; i < 3; ++i)
#pragma unroll
        for (int d = 0; d < 5; ++d) {
            float sq = 0.f, sk = 0.f;
#pragma unroll
            for (int k = 0; k < 5; ++k) {
                sq += Wi[i * 5 + k] * Wq[k * 5 + d];
                sk += Wi[i * 5 + k] * Wk[k * 5 + d];
            }
            Mq[i * 5 + d] = sq;
            Mk[i * 5 + d] = sk;
        }
    float Gp[3][3], vp[3];
#pragma unroll
    for (int i = 0; i < 3; ++i)
#pragma unroll
        for (int j = 0; j < 3; ++j) {
            float s = 0.f;
#pragma unroll
            for (int d = 0; d < 5; ++d) s += Mq[i * 5 + d] * Mk[j * 5 + d];
            Gp[i][j] = s * pf;
        }
#pragma unroll
    for (int j = 0; j < 3; ++j) {
        float s = 0.f;
#pragma unroll
        for (int d = 0; d < 5; ++d) s += cq[d] * Mk[j * 5 + d];
        vp[j] = s * pf;
    }

    // stage all 2000 points (+ b_m) into LDS
#pragma unroll
    for (int r = 0; r < 2; ++r) {
        const int n = r * 1024 + t;
        float4 e = make_float4(0.f, 0.f, 0.f, 0.f);
        if (n < NN) {
            const float p0 = inb[n * 3 + 0];
            const float p1 = inb[n * 3 + 1];
            const float p2 = inb[n * 3 + 2];
            e = make_float4(p0, p1, p2, vp[0] * p0 + vp[1] * p1 + vp[2] * p2);
        }
        sm.a.Ps[n] = e;
    }

    // this lane's 4 query rows: g_r = pf * G^T p_r
    const int wid  = t >> 6;
    const int lane = t & 63;
    float g[4][3];
#pragma unroll
    for (int r = 0; r < 4; ++r) {
        const int row = chunk * ROWS + r * 64 + lane;
        float p0 = 0.f, p1 = 0.f, p2 = 0.f;
        if (row < NN) {
            p0 = inb[row * 3 + 0];
            p1 = inb[row * 3 + 1];
            p2 = inb[row * 3 + 2];
        }
#pragma unroll
        for (int j = 0; j < 3; ++j)
            g[r][j] = p0 * Gp[0][j] + p1 * Gp[1][j] + p2 * Gp[2][j];
    }
    __syncthreads();

    // exp2-sum over this wave's m-chunk (1 b128 read serves 4 rows)
    float acc[4] = {0.f, 0.f, 0.f, 0.f};
    const int m0 = wid * (NN / 16);
#pragma unroll 5
    for (int m = m0; m < m0 + NN / 16; ++m) {
        const float4 P = sm.a.Ps[m];
#pragma unroll
        for (int r = 0; r < 4; ++r) {
            const float e = fmaf(g[r][0], P.x,
                            fmaf(g[r][1], P.y,
                            fmaf(g[r][2], P.z, P.w)));
            acc[r] += __builtin_amdgcn_exp2f(e);
        }
    }
#pragma unroll
    for (int r = 0; r < 4; ++r)
        sm.a.partial[wid][r * 64 + lane] = acc[r];
    __syncthreads();

    // final reduce (fixed wave order, deterministic) + write diag slice
    if (t < ROWS) {
        const int row = chunk * ROWS + t;
        if (row < NN) {
            float sum = sm.a.partial[0][t];
#pragma unroll
            for (int w = 1; w < 16; ++w) sum += sm.a.partial[w][t];
            const float4 Pr = sm.a.Ps[row];
            const float gx = Pr.x * Gp[0][0] + Pr.y * Gp[1][0] + Pr.z * Gp[2][0];
            const float gy = Pr.x * Gp[0][1] + Pr.y * Gp[1][1] + Pr.z * Gp[2][1];
            const float gz = Pr.x * Gp[0][2] + Pr.y * Gp[1][2] + Pr.z * Gp[2][2];
            const float e  = fmaf(gx, Pr.x, fmaf(gy, Pr.y, fmaf(gz, Pr.z, Pr.w)));
            diag[b * NN + row] = __builtin_amdgcn_exp2f(e) / sum;
        }
    }
    __syncthreads();   // drains each thread's outstanding stores (waitcnt+barrier)

    // ===================== arrival: last block of batch proceeds ============
    if (t == 0) {
        __threadfence();                               // release (L2 writeback)
        const unsigned old = atomicAdd(&counters[b], 1u);
        isLast = (old == CHUNKS - 1) ? 1 : 0;
        cnt = 0;
    }
    __syncthreads();
    if (!isLast) return;
    __threadfence();                                   // acquire (inv stale lines)

    // ===================== Phase B: selection for batch b ===================
    const float* dg = diag + (size_t)b * NN;

    // zero histogram + group-sum argmax (disjoint LDS, one barrier)
    sm.b.hist[t] = 0u; sm.b.hist[t + 1024] = 0u;
    float v = -INFINITY; int idx = 0x7fffffff;
    if (t < NN / 5) {
        float s = dg[t * 5 + 0];
        s += dg[t * 5 + 1];
        s += dg[t * 5 + 2];
        s += dg[t * 5 + 3];
        s += dg[t * 5 + 4];
        v = s; idx = t;
    }
#pragma unroll
    for (int off = 32; off > 0; off >>= 1) {
        const float ov = __shfl_down(v, off);
        const int   oi = __shfl_down(idx, off);
        if (ov > v || (ov == v && oi < idx)) { v = ov; idx = oi; }
    }
    if ((t & 63) == 0) { wv[t >> 6] = v; wi_[t >> 6] = idx; }
    __syncthreads();

    if (t == 0) {
        float bv = wv[0]; int bidx = wi_[0];
#pragma unroll
        for (int w = 1; w < 16; ++w) {
            if (wv[w] > bv || (wv[w] == bv && wi_[w] < bidx)) {
                bv = wv[w]; bidx = wi_[w];
            }
        }
        // centroid of winning group (bit-exact numpy mean: rn adds, /5)
        const int base = bidx * 5;
#pragma unroll
        for (int d = 0; d < 3; ++d) {
            float s = inb[(base + 0) * 3 + d];
            s = __fadd_rn(s, inb[(base + 1) * 3 + d]);
            s = __fadd_rn(s, inb[(base + 2) * 3 + d]);
            s = __fadd_rn(s, inb[(base + 3) * 3 + d]);
            s = __fadd_rn(s, inb[(base + 4) * 3 + d]);
            centroid[d] = __fdiv_rn(s, 5.0f);
        }
    }
    __syncthreads();

    const float c0 = centroid[0], c1 = centroid[1], c2 = centroid[2];

    // distances -> keys + histogram on dist_bits[30:20]
#pragma unroll
    for (int r = 0; r < 2; ++r) {
        const int n = r * 1024 + t;
        if (n < NN) {
            const float dx = inb[n * 3 + 0] - c0;
            const float dy = inb[n * 3 + 1] - c1;
            const float dz = inb[n * 3 + 2] - c2;
            // no FMA contraction: bit-exact vs np.linalg.norm ((x2+y2)+z2)
            const float d2 = __fadd_rn(__fadd_rn(__fmul_rn(dx, dx),
                                                 __fmul_rn(dy, dy)),
                                       __fmul_rn(dz, dz));
            const float dist = __fsqrt_rn(d2);
            const unsigned int db = __float_as_uint(dist);
            sm.b.keys[n] = ((unsigned long long)db << 32) | (unsigned int)n;
            atomicAdd(&sm.b.hist[db >> 20], 1u);       // sign=0 -> bin < 2048
        }
    }
    __syncthreads();

    // inclusive scan over 2048 bins (ping-pong Hillis-Steele)
    unsigned int* src = sm.b.hist;
    unsigned int* dst = sm.b.sA;
    for (int stride = 1; stride < NBIN; stride <<= 1) {
#pragma unroll
        for (int r = 0; r < 2; ++r) {
            const int i = r * 1024 + t;
            dst[i] = src[i] + ((i >= stride) ? src[i - stride] : 0u);
        }
        __syncthreads();
        unsigned int* tmp = (dst == sm.b.sA) ? sm.b.sB : sm.b.sA;
        src = dst; dst = (src == sm.b.hist) ? sm.b.sA : tmp;
    }
    const unsigned int* cum = src;

    // threshold bin: first bin with cum >= 110 (unique writer)
#pragma unroll
    for (int r = 0; r < 2; ++r) {
        const int i = r * 1024 + t;
        if (cum[i] >= TOPK_ && (i == 0 || cum[i - 1] < TOPK_)) thrBin = i;
    }
    __syncthreads();

    // compact candidates (all elements in bins <= thrBin)
    const int T = thrBin;
#pragma unroll
    for (int r = 0; r < 2; ++r) {
        const int n = r * 1024 + t;
        if (n < NN) {
            const unsigned long long k = sm.b.keys[n];
            if ((int)(k >> 52) <= T) {
                const int pos = atomicAdd(&cnt, 1);
                sm.b.cand[pos] = k;
            }
        }
    }
    __syncthreads();

    // rank-by-counting among candidates; rank == global rank (keys distinct)
    const int C = cnt;
    for (int i = t; i < C; i += 1024) {
        const unsigned long long ki = sm.b.cand[i];
        int rank = 0;
        for (int j = 0; j < C; ++j) rank += (sm.b.cand[j] < ki);
        if (rank < TOPK_) {
            const int n = (int)(unsigned int)(ki & 0xFFFFFFFFull);
            out[((size_t)b * TOPK_ + rank) * 3 + 0] = inb[n * 3 + 0];
            out[((size_t)b * TOPK_ + rank) * 3 + 1] = inb[n * 3 + 1];
            out[((size_t)b * TOPK_ + rank) * 3 + 2] = inb[n * 3 + 2];
        }
    }
}

// ---------------------------------------------------------------------------
extern "C" void kernel_launch(void* const* d_in, const int* in_sizes, int n_in,
                              void* d_out, int out_size, void* d_ws, size_t ws_size,
                              hipStream_t stream) {
    const float* in_mat = (const float*)d_in[0];
    const float* Wi = (const float*)d_in[1];
    const float* bi = (const float*)d_in[2];
    const float* Wq = (const float*)d_in[3];
    const float* bq = (const float*)d_in[4];
    const float* Wk = (const float*)d_in[5];
    const float* bk = (const float*)d_in[6];
    // Wv, bv, Wo, bo (d_in[7..10]) are dead code in the reference.

    float*        diag     = (float*)d_ws;                          // 256 KB
    unsigned int* counters = (unsigned int*)((char*)d_ws + 256 * 1024);
    float*        out      = (float*)d_out;

    hipMemsetAsync(counters, 0, BB * sizeof(unsigned int), stream);
    k_fused<<<dim3(BB * CHUNKS), 1024, 0, stream>>>(
        in_mat, Wi, bi, Wq, bq, Wk, bk, diag, counters, out);
}

// Round 6
// 109.528 us; speedup vs baseline: 1.2391x; 1.2391x over previous
//
#include <hip/hip_runtime.h>
#include <stdint.h>

#define BB      32
#define NN      2000
#define TOPK_   110
#define NBIN    2048

// ---------------------------------------------------------------------------
// Shared weight folding: scores collapse to a bilinear form in the raw 3-D
// points:  s(n,m)/sqrt5*log2e = g_n . p_m + b_m + (row-const, cancels)
//   g_n = Gp^T p_n,  b_m = vp . p_m
// ---------------------------------------------------------------------------
__device__ __forceinline__ void fold_weights(
    const float* __restrict__ Wi, const float* __restrict__ bi,
    const float* __restrict__ Wq, const float* __restrict__ bq,
    const float* __restrict__ Wk, const float* __restrict__ bk,
    float Gp[3][3], float vp[3])
{
    const float pf = 0.44721359549995793f * 1.4426950408889634f; // 1/sqrt5*log2e
    float Mq[15], Mk[15], cq[5];
#pragma unroll
    for (int d = 0; d < 5; ++d) {
        float s = bq[d];
#pragma unroll
        for (int k = 0; k < 5; ++k) s += bi[k] * Wq[k * 5 + d];
        cq[d] = s;
    }
#pragma unroll
    for (int i = 0; i < 3; ++i)
#pragma unroll
        for (int d = 0; d < 5; ++d) {
            float sq = 0.f, sk = 0.f;
#pragma unroll
            for (int k = 0; k < 5; ++k) {
                sq += Wi[i * 5 + k] * Wq[k * 5 + d];
                sk += Wi[i * 5 + k] * Wk[k * 5 + d];
            }
            Mq[i * 5 + d] = sq;
            Mk[i * 5 + d] = sk;
        }
#pragma unroll
    for (int i = 0; i < 3; ++i)
#pragma unroll
        for (int j = 0; j < 3; ++j) {
            float s = 0.f;
#pragma unroll
            for (int d = 0; d < 5; ++d) s += Mq[i * 5 + d] * Mk[j * 5 + d];
            Gp[i][j] = s * pf;
        }
#pragma unroll
    for (int j = 0; j < 3; ++j) {
        float s = 0.f;
#pragma unroll
        for (int d = 0; d < 5; ++d) s += cq[d] * Mk[j * 5 + d];
        vp[j] = s * pf;
    }
}

// ---------------------------------------------------------------------------
// Kernel 1: partial softmax denominators.
// grid (16, 32): blockIdx.x = rc*2 + ms  (rc = row-chunk of 256, ms = m-half
// of 1000), blockIdx.y = batch. 1024 threads (16 waves), 32 KB LDS, VGPR~44
// -> 2 blocks/CU resident = 32 waves/CU (occupancy cap).
// Each lane carries 4 rows; wave w covers ~62 m's of this block's m-half with
// broadcast LDS reads. Block-internal reduce, then one float atomicAdd per
// row into sums[b][row] (2 contributing blocks per row).
// ---------------------------------------------------------------------------
__global__ __launch_bounds__(1024) void k_diag(
    const float* __restrict__ in_mat,                       // [B,N,3]
    const float* __restrict__ Wi, const float* __restrict__ bi,
    const float* __restrict__ Wq, const float* __restrict__ bq,
    const float* __restrict__ Wk, const float* __restrict__ bk,
    float* __restrict__ sums)                               // [B,N] in d_ws
{
    __shared__ float4 Ps[1024];          // this block's m-half (16 KB)
    __shared__ float  partial[16][256];  // per-wave exp-sums    (16 KB)

    const int b   = blockIdx.y;
    const int rc  = blockIdx.x >> 1;          // row-chunk 0..7
    const int ms  = blockIdx.x & 1;           // m-half 0..1
    const int t   = threadIdx.x;
    const float* inb = in_mat + (size_t)b * NN * 3;

    float Gp[3][3], vp[3];
    fold_weights(Wi, bi, Wq, bq, Wk, bk, Gp, vp);

    // stage this block's 1000 m-points (+ b_m) into LDS
    if (t < 1000) {
        const int n = ms * 1000 + t;
        const float p0 = inb[n * 3 + 0];
        const float p1 = inb[n * 3 + 1];
        const float p2 = inb[n * 3 + 2];
        Ps[t] = make_float4(p0, p1, p2,
                            vp[0] * p0 + vp[1] * p1 + vp[2] * p2);
    }

    // this lane's 4 query rows: g_r = Gp^T p_r
    const int wid  = t >> 6;
    const int lane = t & 63;
    float g[4][3];
#pragma unroll
    for (int r = 0; r < 4; ++r) {
        const int row = rc * 256 + r * 64 + lane;
        float p0 = 0.f, p1 = 0.f, p2 = 0.f;
        if (row < NN) {
            p0 = inb[row * 3 + 0];
            p1 = inb[row * 3 + 1];
            p2 = inb[row * 3 + 2];
        }
#pragma unroll
        for (int j = 0; j < 3; ++j)
            g[r][j] = p0 * Gp[0][j] + p1 * Gp[1][j] + p2 * Gp[2][j];
    }
    __syncthreads();

    // exp2-sum over this wave's m-chunk (62 or 63 m's)
    const int start = wid * 62 + (wid < 8 ? wid : 8);
    const int len   = 62 + (wid < 8 ? 1 : 0);
    float acc[4] = {0.f, 0.f, 0.f, 0.f};
    for (int m = start; m < start + len; ++m) {
        const float4 P = Ps[m];
#pragma unroll
        for (int r = 0; r < 4; ++r) {
            const float e = fmaf(g[r][0], P.x,
                            fmaf(g[r][1], P.y,
                            fmaf(g[r][2], P.z, P.w)));
            acc[r] += __builtin_amdgcn_exp2f(e);
        }
    }
#pragma unroll
    for (int r = 0; r < 4; ++r)
        partial[wid][r * 64 + lane] = acc[r];
    __syncthreads();

    // block-internal reduce + one global atomic per row
    if (t < 256) {
        const int row = rc * 256 + t;
        if (row < NN) {
            float s = partial[0][t];
#pragma unroll
            for (int w = 1; w < 16; ++w) s += partial[w][t];
            atomicAdd(&sums[(size_t)b * NN + row], s);
        }
    }
}

// ---------------------------------------------------------------------------
// Kernel 2: per batch — derive diag = exp2(e_nn)/sum, group argmax, centroid,
// distances, top-110 via histogram-select + rank-by-counting.
// grid 32, block 1024.
// ---------------------------------------------------------------------------
__global__ __launch_bounds__(1024) void k_select(
    const float* __restrict__ in_mat,     // [B,N,3]
    const float* __restrict__ sums,       // [B,N]
    const float* __restrict__ Wi, const float* __restrict__ bi,
    const float* __restrict__ Wq, const float* __restrict__ bq,
    const float* __restrict__ Wk, const float* __restrict__ bk,
    float* __restrict__ out)              // [B,110,3]
{
    __shared__ unsigned long long keys[2048];       // 16 KB
    __shared__ union {
        float              dg[2048];                // phase 1 (8 KB used)
        unsigned long long cand[2048];              // phase 2 (16 KB)
    } u;                                            // dg dead before cand live
    __shared__ unsigned int hist[NBIN];             //  8 KB
    __shared__ unsigned int sA[NBIN];               //  8 KB
    __shared__ unsigned int sB[NBIN];               //  8 KB
    __shared__ float        wv[16];
    __shared__ int          wi_[16];
    __shared__ float        centroid[3];
    __shared__ int          thrBin, cnt;

    const int b = blockIdx.x;
    const int t = threadIdx.x;
    const float* sb  = sums + (size_t)b * NN;
    const float* inb = in_mat + (size_t)b * NN * 3;

    float Gp[3][3], vp[3];
    fold_weights(Wi, bi, Wq, bq, Wk, bk, Gp, vp);

    // zero histogram; derive diag into LDS
    hist[t] = 0u; hist[t + 1024] = 0u;
    if (t == 0) cnt = 0;
#pragma unroll
    for (int r = 0; r < 2; ++r) {
        const int n = r * 1024 + t;
        if (n < NN) {
            const float p0 = inb[n * 3 + 0];
            const float p1 = inb[n * 3 + 1];
            const float p2 = inb[n * 3 + 2];
            const float gx = p0 * Gp[0][0] + p1 * Gp[1][0] + p2 * Gp[2][0];
            const float gy = p0 * Gp[0][1] + p1 * Gp[1][1] + p2 * Gp[2][1];
            const float gz = p0 * Gp[0][2] + p1 * Gp[1][2] + p2 * Gp[2][2];
            const float bw = vp[0] * p0 + vp[1] * p1 + vp[2] * p2;
            const float e  = fmaf(gx, p0, fmaf(gy, p1, fmaf(gz, p2, bw)));
            u.dg[n] = __builtin_amdgcn_exp2f(e) / sb[n];
        }
    }
    __syncthreads();

    // group sums (5 consecutive diag, reference order) + argmax
    float v = -INFINITY; int idx = 0x7fffffff;
    if (t < NN / 5) {
        float s = u.dg[t * 5 + 0];
        s += u.dg[t * 5 + 1];
        s += u.dg[t * 5 + 2];
        s += u.dg[t * 5 + 3];
        s += u.dg[t * 5 + 4];
        v = s; idx = t;
    }
#pragma unroll
    for (int off = 32; off > 0; off >>= 1) {
        const float ov = __shfl_down(v, off);
        const int   oi = __shfl_down(idx, off);
        if (ov > v || (ov == v && oi < idx)) { v = ov; idx = oi; }
    }
    if ((t & 63) == 0) { wv[t >> 6] = v; wi_[t >> 6] = idx; }
    __syncthreads();

    if (t == 0) {
        float bv = wv[0]; int bidx = wi_[0];
#pragma unroll
        for (int w = 1; w < 16; ++w) {
            if (wv[w] > bv || (wv[w] == bv && wi_[w] < bidx)) {
                bv = wv[w]; bidx = wi_[w];
            }
        }
        // centroid of winning group (bit-exact numpy mean: rn adds, /5)
        const int base = bidx * 5;
#pragma unroll
        for (int d = 0; d < 3; ++d) {
            float s = inb[(base + 0) * 3 + d];
            s = __fadd_rn(s, inb[(base + 1) * 3 + d]);
            s = __fadd_rn(s, inb[(base + 2) * 3 + d]);
            s = __fadd_rn(s, inb[(base + 3) * 3 + d]);
            s = __fadd_rn(s, inb[(base + 4) * 3 + d]);
            centroid[d] = __fdiv_rn(s, 5.0f);
        }
    }
    __syncthreads();

    const float c0 = centroid[0], c1 = centroid[1], c2 = centroid[2];

    // distances -> keys + histogram on dist_bits[30:20]  (dg dead after here)
#pragma unroll
    for (int r = 0; r < 2; ++r) {
        const int n = r * 1024 + t;
        if (n < NN) {
            const float dx = inb[n * 3 + 0] - c0;
            const float dy = inb[n * 3 + 1] - c1;
            const float dz = inb[n * 3 + 2] - c2;
            // no FMA contraction: bit-exact vs np.linalg.norm ((x2+y2)+z2)
            const float d2 = __fadd_rn(__fadd_rn(__fmul_rn(dx, dx),
                                                 __fmul_rn(dy, dy)),
                                       __fmul_rn(dz, dz));
            const float dist = __fsqrt_rn(d2);
            const unsigned int db = __float_as_uint(dist);
            keys[n] = ((unsigned long long)db << 32) | (unsigned int)n;
            atomicAdd(&hist[db >> 20], 1u);        // sign=0 -> bin < 2048
        }
    }
    __syncthreads();

    // inclusive scan over 2048 bins (ping-pong Hillis-Steele)
    unsigned int* src = hist;
    unsigned int* dst = sA;
    for (int stride = 1; stride < NBIN; stride <<= 1) {
#pragma unroll
        for (int r = 0; r < 2; ++r) {
            const int i = r * 1024 + t;
            dst[i] = src[i] + ((i >= stride) ? src[i - stride] : 0u);
        }
        __syncthreads();
        unsigned int* tmp = (dst == sA) ? sB : sA;
        src = dst; dst = (src == hist) ? sA : tmp;
    }
    const unsigned int* cum = src;

    // threshold bin: first bin with cum >= 110 (unique writer)
#pragma unroll
    for (int r = 0; r < 2; ++r) {
        const int i = r * 1024 + t;
        if (cum[i] >= TOPK_ && (i == 0 || cum[i - 1] < TOPK_)) thrBin = i;
    }
    __syncthreads();

    // compact candidates (all elements in bins <= thrBin) into u.cand
    const int T = thrBin;
#pragma unroll
    for (int r = 0; r < 2; ++r) {
        const int n = r * 1024 + t;
        if (n < NN) {
            const unsigned long long k = keys[n];
            if ((int)(k >> 52) <= T) {
                const int pos = atomicAdd(&cnt, 1);
                u.cand[pos] = k;
            }
        }
    }
    __syncthreads();

    // rank-by-counting among candidates; rank == global rank (keys distinct)
    const int C = cnt;
    for (int i = t; i < C; i += 1024) {
        const unsigned long long ki = u.cand[i];
        int rank = 0;
        for (int j = 0; j < C; ++j) rank += (u.cand[j] < ki);
        if (rank < TOPK_) {
            const int n = (int)(unsigned int)(ki & 0xFFFFFFFFull);
            out[((size_t)b * TOPK_ + rank) * 3 + 0] = inb[n * 3 + 0];
            out[((size_t)b * TOPK_ + rank) * 3 + 1] = inb[n * 3 + 1];
            out[((size_t)b * TOPK_ + rank) * 3 + 2] = inb[n * 3 + 2];
        }
    }
}

// ---------------------------------------------------------------------------
extern "C" void kernel_launch(void* const* d_in, const int* in_sizes, int n_in,
                              void* d_out, int out_size, void* d_ws, size_t ws_size,
                              hipStream_t stream) {
    const float* in_mat = (const float*)d_in[0];
    const float* Wi = (const float*)d_in[1];
    const float* bi = (const float*)d_in[2];
    const float* Wq = (const float*)d_in[3];
    const float* bq = (const float*)d_in[4];
    const float* Wk = (const float*)d_in[5];
    const float* bk = (const float*)d_in[6];
    // Wv, bv, Wo, bo (d_in[7..10]) are dead code in the reference.

    float* sums = (float*)d_ws;               // B*N floats = 256 KB
    float* out  = (float*)d_out;

    hipMemsetAsync(sums, 0, (size_t)BB * NN * sizeof(float), stream);
    k_diag<<<dim3(16, BB), 1024, 0, stream>>>(
        in_mat, Wi, bi, Wq, bq, Wk, bk, sums);
    k_select<<<BB, 1024, 0, stream>>>(
        in_mat, sums, Wi, bi, Wq, bq, Wk, bk, out);
}